// Round 17
// baseline (294.584 us; speedup 1.0000x reference)
//
#include <hip/hip_runtime.h>
#include <stdint.h>

#define IN_F   4096
#define OUT_F  4096
#define M_TOT  8192
#define KDIM   4096

typedef float          f32x4  __attribute__((ext_vector_type(4)));
typedef int            i32x4  __attribute__((ext_vector_type(4)));
typedef unsigned short u16x8  __attribute__((ext_vector_type(8)));
typedef __bf16         bf16x8 __attribute__((ext_vector_type(8)));

// round-to-nearest-even f32 -> bf16
__device__ __forceinline__ unsigned short f2bf(float f) {
  uint32_t u = __builtin_bit_cast(uint32_t, f);
  u = (u + 0x7FFFu + ((u >> 16) & 1u)) >> 16;
  return (unsigned short)u;
}
__device__ __forceinline__ float bf2f(unsigned short s) {
  return __builtin_bit_cast(float, (uint32_t)s << 16);
}

// async global->LDS; dest = wave-uniform base, HW adds lane*16
__device__ __forceinline__ void gld_lds16(const void* g, void* l) {
  __builtin_amdgcn_global_load_lds((const __attribute__((address_space(1))) void*)g,
                                   (__attribute__((address_space(3))) void*)l,
                                   16, 0, 0);
}

// ---------- kernel 1: x (fp32) -> bf16, 8 elems/thread ----------
__global__ __launch_bounds__(256) void k_xcast(const f32x4* __restrict__ x,
                                               u16x8* __restrict__ xb) {
  int t = blockIdx.x * 256 + threadIdx.x;
  f32x4 a = x[2 * t];
  f32x4 b = x[2 * t + 1];
  u16x8 o;
  o[0] = f2bf(a[0]); o[1] = f2bf(a[1]); o[2] = f2bf(a[2]); o[3] = f2bf(a[3]);
  o[4] = f2bf(b[0]); o[5] = f2bf(b[1]); o[6] = f2bf(b[2]); o[7] = f2bf(b[3]);
  xb[t] = o;
}

// ---------- kernel 2: L[o][i] = bf16( 2.0 * sum_r A[i][r]*B[r][o] ) ----------
__global__ __launch_bounds__(256) void k_lora(const float* __restrict__ A,   // [IN_F][16]
                                              const float* __restrict__ Bm,  // [16][OUT_F]
                                              unsigned short* __restrict__ L) { // [OUT_F][IN_F] bf16
  __shared__ float sB[16][64];
  const int ib = blockIdx.x * 256;
  const int ob = blockIdx.y * 64;
  const int t  = threadIdx.x;
  for (int j = 0; j < 4; ++j) {
    int idx = t + j * 256;
    int r = idx >> 6, oc = idx & 63;
    sB[r][oc] = Bm[r * OUT_F + ob + oc];
  }
  float a[16];
  const f32x4* Ap = (const f32x4*)(A + (size_t)(ib + t) * 16);
  #pragma unroll
  for (int j = 0; j < 4; ++j) {
    f32x4 v = Ap[j];
    a[4*j+0] = v[0]; a[4*j+1] = v[1]; a[4*j+2] = v[2]; a[4*j+3] = v[3];
  }
  __syncthreads();
  unsigned short* Lp = L + (size_t)ob * IN_F + ib + t;
  #pragma unroll 4
  for (int oc = 0; oc < 64; ++oc) {
    float acc = 0.f;
    #pragma unroll
    for (int r = 0; r < 16; ++r) acc += a[r] * sB[r][oc];
    Lp[(size_t)oc * IN_F] = f2bf(acc * 2.0f);   // LORA_SCALE = 32/16
  }
}

// ---------- kernel 3: dequant INT4 + merge L -> Wc bf16 [OUT_F][IN_F] ----------
__global__ __launch_bounds__(256) void k_dequant(const int* __restrict__ idx,
                                                 const float* __restrict__ cb,
                                                 const float* __restrict__ scales,
                                                 const unsigned short* __restrict__ L,
                                                 unsigned short* __restrict__ Wc) {
  __shared__ float scb[16];
  const int t = blockIdx.x * 256 + threadIdx.x;
  if (threadIdx.x < 16) scb[threadIdx.x] = cb[threadIdx.x];
  __syncthreads();
  i32x4 w = ((const i32x4*)idx)[t];
  float sc = scales[t >> 4];
  u16x8 lw = ((const u16x8*)L)[t];
  u16x8 o;
  #pragma unroll
  for (int j = 0; j < 4; ++j) {
    int word = w[j];
    float v0 = scb[word & 15] * sc + bf2f(lw[2 * j]);
    float v1 = scb[(word >> 4) & 15] * sc + bf2f(lw[2 * j + 1]);
    o[2 * j]     = f2bf(v0);
    o[2 * j + 1] = f2bf(v1);
  }
  ((u16x8*)Wc)[t] = o;
}

// ---------- kernel 4: 256x256 bf16 GEMM, persistent 2-tile blocks (R16 K-loop) ----------
// C[m][n] = sum_k A[m][k]*B[n][k] + bias[n];  A:[8192][4096] bf16, B:[4096][4096] bf16.
// 512 thr = 8 waves (2M x 4N); wave out 128x64; BK=64; 128 KiB LDS dbuf.
// LDS: A buf c at c*32768 (256 rows x 128B); B buf c at 65536+c*32768. XOR-8 swizzle
// (slot^(row&7)) via pre-swizzled global source + XOR on ds_read — measured 0 conflicts.
// One LGKM0+VMC0+BARR per K-tile; stage targets only buf c^1 (readers retired last tile).
//
// ROUND-17: grid 256 blocks (exactly 1/CU); each block computes (bm,bn) then (bm,bn+8).
// Pass-1's tile-0 is staged into buf0 DURING pass-0's final K-tile (buf0 dead: its t62
// readers retired at t62's LGKM0+BARR; t63 reads only buf1), so pass-1 starts with
// zero prologue wait. Epilogue-0 scratch in A-buf1 (disjoint from the in-flight stage);
// __syncthreads() (real fence + full drain) brackets each epilogue (R7 lesson).

#define BARR()  __builtin_amdgcn_s_barrier()
#define LGKM0() asm volatile("s_waitcnt lgkmcnt(0)" ::: "memory")
#define VMC0()  asm volatile("s_waitcnt vmcnt(0)" ::: "memory")

#define STAGE_A(kt, ha, c) do {                                                          \
  gld_lds16(Ag + (size_t)((ha) * 128) * KDIM + (kt) * 64,                                \
            smem + (c) * 32768 + (ha) * 16384 + ldsw);                                   \
  gld_lds16(Ag + (size_t)((ha) * 128 + 64) * KDIM + (kt) * 64,                           \
            smem + (c) * 32768 + (ha) * 16384 + 8192 + ldsw);                            \
} while (0)

#define STAGE_B(kt, hb, c) do {                                                          \
  gld_lds16(Bgv + (size_t)((hb) * 128) * KDIM + (kt) * 64,                               \
            smem + 65536 + (c) * 32768 + (hb) * 16384 + ldsw);                           \
  gld_lds16(Bgv + (size_t)((hb) * 128 + 64) * KDIM + (kt) * 64,                          \
            smem + 65536 + (c) * 32768 + (hb) * 16384 + 8192 + ldsw);                    \
} while (0)

// 4 B-frag reads for one kk half (COFF = swizzled byte col)
#define READ_B4(DST, c, COFF) do {                                                       \
  const char* _p = smem + 65536 + (c) * 32768 + rowB;                                    \
  _Pragma("unroll")                                                                      \
  for (int n = 0; n < 4; ++n)                                                            \
    DST[n] = *(const bf16x8*)(_p + n * 2048 + (COFF));                                   \
} while (0)

// 8 A-frag reads for one kk half
#define READ_A8(DST, c, COFF) do {                                                       \
  const char* _p = smem + (c) * 32768 + rowA;                                            \
  _Pragma("unroll")                                                                      \
  for (int m16 = 0; m16 < 8; ++m16)                                                      \
    DST[m16] = *(const bf16x8*)(_p + m16 * 2048 + (COFF));                               \
} while (0)

#define MFMA32(AF, BF) do {                                                              \
  __builtin_amdgcn_s_setprio(1);                                                         \
  _Pragma("unroll")                                                                      \
  for (int m16 = 0; m16 < 8; ++m16)                                                      \
    _Pragma("unroll")                                                                    \
    for (int n = 0; n < 4; ++n)                                                          \
      acc[m16][n] = __builtin_amdgcn_mfma_f32_16x16x32_bf16(AF[m16], BF[n],              \
                                                            acc[m16][n], 0, 0, 0);      \
  __builtin_amdgcn_s_setprio(0);                                                         \
} while (0)

// Tile t on buf c (R16-verified). Stage t+1 -> buf c^1 (readers drained at t-1's
// LGKM0+BARR). End: LGKM0 retires this tile's reads; VMC0 completes stage(t+1);
// BARR makes both cross-wave. Uniform control flow.
#define TILE5(t_, c_, doStage) do {                                                      \
  if (doStage) {                                                                         \
    STAGE_B((t_) + 1, 0, (c_) ^ 1); STAGE_B((t_) + 1, 1, (c_) ^ 1);                      \
    STAGE_A((t_) + 1, 0, (c_) ^ 1); STAGE_A((t_) + 1, 1, (c_) ^ 1);                      \
  }                                                                                      \
  READ_B4(bfrX, c_, coffX); READ_A8(afX, c_, coffX);                                     \
  MFMA32(afX, bfrX);                                                                     \
  READ_B4(bfrY, c_, coffY); READ_A8(afY, c_, coffY);                                     \
  MFMA32(afY, bfrY);                                                                     \
  LGKM0(); VMC0(); BARR();                                                               \
} while (0)

// epilogue (R8-verified form): LDS-repack at EPSOFF + coalesced dwordx4 stores
#define EPI(EPSOFF, COL0) do {                                                           \
  char* eps = smem + (EPSOFF) + wv * 4096;    /* [16 rows][64 f32] per wave */           \
  const int row0e = bm * 256 + wm * 128;                                                 \
  const int col0e = (COL0) + wn * 64;                                                    \
  const f32x4 bias4 = *(const f32x4*)(bias + col0e + r * 4);                             \
  _Pragma("unroll")                                                                      \
  for (int mi = 0; mi < 8; ++mi) {                                                       \
    _Pragma("unroll")                                                                    \
    for (int j = 0; j < 4; ++j)                                                          \
      _Pragma("unroll")                                                                  \
      for (int ni = 0; ni < 4; ++ni)                                                     \
        *(float*)(eps + (((q * 4 + j) * 64) + ni * 16 + r) * 4) = acc[mi][ni][j];        \
    LGKM0();                                                                             \
    __builtin_amdgcn_sched_barrier(0);                                                   \
    _Pragma("unroll")                                                                    \
    for (int p = 0; p < 4; ++p) {                                                        \
      const int row = p * 4 + q;                                                         \
      f32x4 v = *(const f32x4*)(eps + row * 256 + r * 16);                               \
      v[0] += bias4[0]; v[1] += bias4[1]; v[2] += bias4[2]; v[3] += bias4[3];            \
      *(f32x4*)(C + (size_t)(row0e + mi * 16 + row) * OUT_F + col0e + r * 4) = v;        \
    }                                                                                    \
    asm volatile("" ::: "memory");            /* gather(mi) before scatter(mi+1) */      \
  }                                                                                      \
} while (0)

#define ZERO_ACC() do {                                                                  \
  _Pragma("unroll")                                                                      \
  for (int m = 0; m < 8; ++m)                                                            \
    _Pragma("unroll")                                                                    \
    for (int n = 0; n < 4; ++n)                                                          \
      acc[m][n] = (f32x4){0.f, 0.f, 0.f, 0.f};                                           \
} while (0)

__global__ __launch_bounds__(512, 2) void k_gemm(const unsigned short* __restrict__ A,
                                                 const unsigned short* __restrict__ B,
                                                 const float* __restrict__ bias,
                                                 float* __restrict__ C) {
  __shared__ char smem[131072];   // static 128 KiB
  const int tid  = threadIdx.x;
  const int lane = tid & 63;
  const int wv   = tid >> 6;     // 0..7
  const int wm   = wv >> 2;      // 0..1
  const int wn   = wv & 3;       // 0..3
  const int r    = lane & 15;
  const int q    = lane >> 4;
  const int xr   = r & 7;
  const int coff0 = (q ^ xr) << 4;          // byte col kk=0 (swizzled)
  const int coff1 = ((q + 4) ^ xr) << 4;    // byte col kk=1
  const int coffX = (wv & 1) ? coff1 : coff0;
  const int coffY = (wv & 1) ? coff0 : coff1;
  const int rowA = (wm * 128 + r) * 128;    // byte row base in A tile
  const int rowB = (wn * 64 + r) * 128;     // byte row base in B tile
  const int srow = tid >> 3;                // 0..63 staging row
  const int scol = ((tid & 7) ^ ((tid >> 3) & 7)) * 8;  // pre-swizzled global elem col
  const int ldsw = wv * 1024;               // wave's byte slot per staging call
  const int bm  = blockIdx.x;               // 0..31
  const int bn0 = blockIdx.y;               // 0..7 ; pass 1 uses bn0+8

  const unsigned short* Ag  = A + (size_t)(bm * 256 + srow) * KDIM + scol;
  const unsigned short* Bg0 = B + (size_t)(bn0 * 256 + srow) * KDIM + scol;
  const unsigned short* Bg1 = Bg0 + (size_t)(8 * 256) * KDIM;
  const unsigned short* Bgv = Bg0;          // panel pointer used by STAGE_B

  bf16x8 afX[8], afY[8], bfrX[4], bfrY[4];
  f32x4 acc[8][4];
  ZERO_ACC();

  // ---- pass 0 prologue: stage tile 0 into buf0 ----
  STAGE_B(0, 0, 0); STAGE_B(0, 1, 0); STAGE_A(0, 0, 0); STAGE_A(0, 1, 0);
  VMC0();
  BARR();

  // ---- pass 0 K-loop (tiles 0..62 standard; 63 custom) ----
  #pragma unroll 1
  for (int t = 0; t < 62; t += 2) {
    TILE5(t,     0, 1);
    TILE5(t + 1, 1, 1);
  }
  TILE5(62, 0, 1);            // stages t63 -> buf1; VMC0 drains it

  // tile 63 (buf1) + cross-pass stage: pass-1 tile0 -> buf0 (dead: t62 readers
  // retired at t62's LGKM0+BARR; t63 reads only buf1). Loads complete under
  // t63's MFMAs; __syncthreads() (full drain + compiler fence) closes the pass.
  Bgv = Bg1;
  STAGE_B(0, 0, 0); STAGE_B(0, 1, 0); STAGE_A(0, 0, 0); STAGE_A(0, 1, 0);
  READ_B4(bfrX, 1, coffX); READ_A8(afX, 1, coffX);
  MFMA32(afX, bfrX);
  READ_B4(bfrY, 1, coffY); READ_A8(afY, 1, coffY);
  MFMA32(afY, bfrY);
  __syncthreads();

  // ---- pass 0 epilogue: scratch in A-buf1 [32768,65536) (disjoint from the
  // freshly staged buf0 {A:[0,32K), B:[65536,98304)}; buf1 readers just drained)
  EPI(32768, bn0 * 256);
  __syncthreads();            // epilogue ds ops retired before pass-1 stages buf1
  ZERO_ACC();

  // ---- pass 1 K-loop: tile0 already resident in buf0, zero prologue wait ----
  #pragma unroll 1
  for (int t = 0; t < 62; t += 2) {
    TILE5(t,     0, 1);
    TILE5(t + 1, 1, 1);
  }
  TILE5(62, 0, 1);
  TILE5(63, 1, 0);

  // ---- pass 1 epilogue: scratch in A-buf0 (R16-verified placement) ----
  __syncthreads();
  EPI(0, (bn0 + 8) * 256);
}

extern "C" void kernel_launch(void* const* d_in, const int* in_sizes, int n_in,
                              void* d_out, int out_size, void* d_ws, size_t ws_size,
                              hipStream_t stream) {
  const float* x    = (const float*)d_in[0];
  const int*   idx  = (const int*)d_in[1];
  const float* cb   = (const float*)d_in[2];
  const float* scl  = (const float*)d_in[3];
  const float* lA   = (const float*)d_in[4];
  const float* lB   = (const float*)d_in[5];
  const float* bias = (const float*)d_in[6];
  float* out = (float*)d_out;

  unsigned short* xb = (unsigned short*)d_ws;
  unsigned short* Wc = (unsigned short*)((char*)d_ws + (size_t)M_TOT * KDIM * 2);
  unsigned short* Lbuf = (unsigned short*)d_out;  // bf16 LoRA scratch; overwritten by k_gemm

  k_xcast<<<16384, 256, 0, stream>>>((const f32x4*)x, (u16x8*)xb);
  k_lora<<<dim3(16, 64), 256, 0, stream>>>(lA, lB, Lbuf);
  k_dequant<<<8192, 256, 0, stream>>>(idx, cb, scl, Lbuf, Wc);
  k_gemm<<<dim3(32, 8), 512, 0, stream>>>(xb, Wc, bias, out);
}

// Round 18
// 280.258 us; speedup vs baseline: 1.0511x; 1.0511x over previous
//
#include <hip/hip_runtime.h>
#include <stdint.h>

#define IN_F   4096
#define OUT_F  4096
#define M_TOT  8192
#define KDIM   4096

typedef float          f32x4  __attribute__((ext_vector_type(4)));
typedef int            i32x4  __attribute__((ext_vector_type(4)));
typedef unsigned short u16x8  __attribute__((ext_vector_type(8)));
typedef __bf16         bf16x8 __attribute__((ext_vector_type(8)));

// round-to-nearest-even f32 -> bf16
__device__ __forceinline__ unsigned short f2bf(float f) {
  uint32_t u = __builtin_bit_cast(uint32_t, f);
  u = (u + 0x7FFFu + ((u >> 16) & 1u)) >> 16;
  return (unsigned short)u;
}
__device__ __forceinline__ float bf2f(unsigned short s) {
  return __builtin_bit_cast(float, (uint32_t)s << 16);
}

// async global->LDS; dest = wave-uniform base, HW adds lane*16
__device__ __forceinline__ void gld_lds16(const void* g, void* l) {
  __builtin_amdgcn_global_load_lds((const __attribute__((address_space(1))) void*)g,
                                   (__attribute__((address_space(3))) void*)l,
                                   16, 0, 0);
}

// ---------- kernel 1: x (fp32) -> bf16, 8 elems/thread ----------
__global__ __launch_bounds__(256) void k_xcast(const f32x4* __restrict__ x,
                                               u16x8* __restrict__ xb) {
  int t = blockIdx.x * 256 + threadIdx.x;
  f32x4 a = x[2 * t];
  f32x4 b = x[2 * t + 1];
  u16x8 o;
  o[0] = f2bf(a[0]); o[1] = f2bf(a[1]); o[2] = f2bf(a[2]); o[3] = f2bf(a[3]);
  o[4] = f2bf(b[0]); o[5] = f2bf(b[1]); o[6] = f2bf(b[2]); o[7] = f2bf(b[3]);
  xb[t] = o;
}

// ---------- kernel 2: L[o][i] = bf16( 2.0 * sum_r A[i][r]*B[r][o] ) ----------
__global__ __launch_bounds__(256) void k_lora(const float* __restrict__ A,   // [IN_F][16]
                                              const float* __restrict__ Bm,  // [16][OUT_F]
                                              unsigned short* __restrict__ L) { // [OUT_F][IN_F] bf16
  __shared__ float sB[16][64];
  const int ib = blockIdx.x * 256;
  const int ob = blockIdx.y * 64;
  const int t  = threadIdx.x;
  for (int j = 0; j < 4; ++j) {
    int idx = t + j * 256;
    int r = idx >> 6, oc = idx & 63;
    sB[r][oc] = Bm[r * OUT_F + ob + oc];
  }
  float a[16];
  const f32x4* Ap = (const f32x4*)(A + (size_t)(ib + t) * 16);
  #pragma unroll
  for (int j = 0; j < 4; ++j) {
    f32x4 v = Ap[j];
    a[4*j+0] = v[0]; a[4*j+1] = v[1]; a[4*j+2] = v[2]; a[4*j+3] = v[3];
  }
  __syncthreads();
  unsigned short* Lp = L + (size_t)ob * IN_F + ib + t;
  #pragma unroll 4
  for (int oc = 0; oc < 64; ++oc) {
    float acc = 0.f;
    #pragma unroll
    for (int r = 0; r < 16; ++r) acc += a[r] * sB[r][oc];
    Lp[(size_t)oc * IN_F] = f2bf(acc * 2.0f);   // LORA_SCALE = 32/16
  }
}

// ---------- kernel 3: dequant INT4 + merge L -> Wc bf16 [OUT_F][IN_F] ----------
__global__ __launch_bounds__(256) void k_dequant(const int* __restrict__ idx,
                                                 const float* __restrict__ cb,
                                                 const float* __restrict__ scales,
                                                 const unsigned short* __restrict__ L,
                                                 unsigned short* __restrict__ Wc) {
  __shared__ float scb[16];
  const int t = blockIdx.x * 256 + threadIdx.x;
  if (threadIdx.x < 16) scb[threadIdx.x] = cb[threadIdx.x];
  __syncthreads();
  i32x4 w = ((const i32x4*)idx)[t];
  float sc = scales[t >> 4];
  u16x8 lw = ((const u16x8*)L)[t];
  u16x8 o;
  #pragma unroll
  for (int j = 0; j < 4; ++j) {
    int word = w[j];
    float v0 = scb[word & 15] * sc + bf2f(lw[2 * j]);
    float v1 = scb[(word >> 4) & 15] * sc + bf2f(lw[2 * j + 1]);
    o[2 * j]     = f2bf(v0);
    o[2 * j + 1] = f2bf(v1);
  }
  ((u16x8*)Wc)[t] = o;
}

// ---------- kernel 4: 256x256 bf16 GEMM (best-measured config, R12/R16) ----------
// C[m][n] = sum_k A[m][k]*B[n][k] + bias[n];  A:[8192][4096] bf16, B:[4096][4096] bf16.
// 512 thr = 8 waves (2M x 4N); wave out 128x64; BK=64; 128 KiB LDS dbuf.
// LDS: A buf c at c*32768 (256 rows x 128B); B buf c at 65536+c*32768. XOR-8 swizzle
// (slot^(row&7)) via pre-swizzled global source + XOR on ds_read — measured 0 conflicts.
// One LGKM0+VMC0+BARR per K-tile; stage targets only buf c^1 (readers retired last
// tile). Measured (reproduced 3x): k_gemm ~231 µs (1190 TF), MfmaUtil ~55%,
// FETCH ~197 MB (per-XCD L2 floor), total ~280 µs.
// Plateau note: 9 structural variants (phase splits, within-wave pipelines, wave
// stagger, 32x32 shape, B-direct, persistent 2-tile) all land <=55% or regress;
// binding term is LDS-read issue phase-locked against MFMA by the barrier-coupled
// dbuf. Known paths beyond: m201-exact interleave / inline-asm K-loop (AITER-style).

#define BARR()  __builtin_amdgcn_s_barrier()
#define LGKM0() asm volatile("s_waitcnt lgkmcnt(0)" ::: "memory")
#define VMC0()  asm volatile("s_waitcnt vmcnt(0)" ::: "memory")

#define STAGE_A(kt, ha, c) do {                                                          \
  gld_lds16(Ag + (size_t)((ha) * 128) * KDIM + (kt) * 64,                                \
            smem + (c) * 32768 + (ha) * 16384 + ldsw);                                   \
  gld_lds16(Ag + (size_t)((ha) * 128 + 64) * KDIM + (kt) * 64,                           \
            smem + (c) * 32768 + (ha) * 16384 + 8192 + ldsw);                            \
} while (0)

#define STAGE_B(kt, hb, c) do {                                                          \
  gld_lds16(Bg + (size_t)((hb) * 128) * KDIM + (kt) * 64,                                \
            smem + 65536 + (c) * 32768 + (hb) * 16384 + ldsw);                           \
  gld_lds16(Bg + (size_t)((hb) * 128 + 64) * KDIM + (kt) * 64,                           \
            smem + 65536 + (c) * 32768 + (hb) * 16384 + 8192 + ldsw);                    \
} while (0)

// 4 B-frag reads for one kk half (COFF = swizzled byte col)
#define READ_B4(DST, c, COFF) do {                                                       \
  const char* _p = smem + 65536 + (c) * 32768 + rowB;                                    \
  _Pragma("unroll")                                                                      \
  for (int n = 0; n < 4; ++n)                                                            \
    DST[n] = *(const bf16x8*)(_p + n * 2048 + (COFF));                                   \
} while (0)

// 8 A-frag reads for one kk half
#define READ_A8(DST, c, COFF) do {                                                       \
  const char* _p = smem + (c) * 32768 + rowA;                                            \
  _Pragma("unroll")                                                                      \
  for (int m16 = 0; m16 < 8; ++m16)                                                      \
    DST[m16] = *(const bf16x8*)(_p + m16 * 2048 + (COFF));                               \
} while (0)

#define MFMA32(AF, BF) do {                                                              \
  __builtin_amdgcn_s_setprio(1);                                                         \
  _Pragma("unroll")                                                                      \
  for (int m16 = 0; m16 < 8; ++m16)                                                      \
    _Pragma("unroll")                                                                    \
    for (int n = 0; n < 4; ++n)                                                          \
      acc[m16][n] = __builtin_amdgcn_mfma_f32_16x16x32_bf16(AF[m16], BF[n],              \
                                                            acc[m16][n], 0, 0, 0);      \
  __builtin_amdgcn_s_setprio(0);                                                         \
} while (0)

// Tile t on buf c. Stage t+1 -> buf c^1 (its readers drained at t-1's LGKM0+BARR).
// Per-wave: read half X (4 B + 8 A), MFMA 32, read half Y, MFMA 32. X/Y swap by
// wave parity. End: LGKM0 retires this tile's reads before t+1 stages buf c;
// VMC0 completes stage(t+1) before BARR releases t+1. Uniform control flow.
#define TILE5(t_, c_, doStage) do {                                                      \
  if (doStage) {                                                                         \
    STAGE_B((t_) + 1, 0, (c_) ^ 1); STAGE_B((t_) + 1, 1, (c_) ^ 1);                      \
    STAGE_A((t_) + 1, 0, (c_) ^ 1); STAGE_A((t_) + 1, 1, (c_) ^ 1);                      \
  }                                                                                      \
  READ_B4(bfrX, c_, coffX); READ_A8(afX, c_, coffX);                                     \
  MFMA32(afX, bfrX);                                                                     \
  READ_B4(bfrY, c_, coffY); READ_A8(afY, c_, coffY);                                     \
  MFMA32(afY, bfrY);                                                                     \
  LGKM0(); VMC0(); BARR();                                                               \
} while (0)

__global__ __launch_bounds__(512, 2) void k_gemm(const unsigned short* __restrict__ A,
                                                 const unsigned short* __restrict__ B,
                                                 const float* __restrict__ bias,
                                                 float* __restrict__ C) {
  __shared__ char smem[131072];   // static 128 KiB
  const int tid  = threadIdx.x;
  const int lane = tid & 63;
  const int wv   = tid >> 6;     // 0..7
  const int wm   = wv >> 2;      // 0..1
  const int wn   = wv & 3;       // 0..3
  const int r    = lane & 15;
  const int q    = lane >> 4;
  const int xr   = r & 7;
  const int coff0 = (q ^ xr) << 4;          // byte col kk=0 (swizzled)
  const int coff1 = ((q + 4) ^ xr) << 4;    // byte col kk=1
  const int coffX = (wv & 1) ? coff1 : coff0;
  const int coffY = (wv & 1) ? coff0 : coff1;
  const int rowA = (wm * 128 + r) * 128;    // byte row base in A tile
  const int rowB = (wn * 64 + r) * 128;     // byte row base in B tile
  const int srow = tid >> 3;                // 0..63 staging row
  const int scol = ((tid & 7) ^ ((tid >> 3) & 7)) * 8;  // pre-swizzled global elem col
  const int ldsw = wv * 1024;               // wave's byte slot per staging call
  const int bm = blockIdx.x;                // 0..31
  const int bn = blockIdx.y;                // 0..15

  const unsigned short* Ag = A + (size_t)(bm * 256 + srow) * KDIM + scol;
  const unsigned short* Bg = B + (size_t)(bn * 256 + srow) * KDIM + scol;

  bf16x8 afX[8], afY[8], bfrX[4], bfrY[4];
  f32x4 acc[8][4];
  #pragma unroll
  for (int m = 0; m < 8; ++m)
    #pragma unroll
    for (int n = 0; n < 4; ++n)
      acc[m][n] = (f32x4){0.f, 0.f, 0.f, 0.f};

  // prologue: stage tile 0 into buf0, wait, one barrier
  STAGE_B(0, 0, 0); STAGE_B(0, 1, 0); STAGE_A(0, 0, 0); STAGE_A(0, 1, 0);
  VMC0();
  BARR();

  #pragma unroll 1
  for (int t = 0; t < 62; t += 2) {
    TILE5(t,     0, 1);
    TILE5(t + 1, 1, 1);
  }
  TILE5(62, 0, 1);
  TILE5(63, 1, 0);

  // ---- epilogue: LDS-repack + coalesced dwordx4 stores (R8-verified) ----
  // eps in A-buf0 [0,32KiB): last buf0 reads at t62 (drained at t62's LGKM0+BARR);
  // last buf0 stage writes issued t61 (drained t61 VMC0). __syncthreads() supplies
  // the compiler-level fence raw s_barrier lacks.
  __syncthreads();
  {
    char* eps = smem + wv * 4096;             // [16 rows][64 f32] per wave
    const int row0 = bm * 256 + wm * 128;
    const int col0 = bn * 256 + wn * 64;
    const f32x4 bias4 = *(const f32x4*)(bias + col0 + r * 4);
    #pragma unroll
    for (int mi = 0; mi < 8; ++mi) {
      #pragma unroll
      for (int j = 0; j < 4; ++j)
        #pragma unroll
        for (int ni = 0; ni < 4; ++ni)
          *(float*)(eps + (((q * 4 + j) * 64) + ni * 16 + r) * 4) = acc[mi][ni][j];
      LGKM0();
      __builtin_amdgcn_sched_barrier(0);
      #pragma unroll
      for (int p = 0; p < 4; ++p) {
        const int row = p * 4 + q;            // 0..15
        f32x4 v = *(const f32x4*)(eps + row * 256 + r * 16);
        v[0] += bias4[0]; v[1] += bias4[1]; v[2] += bias4[2]; v[3] += bias4[3];
        *(f32x4*)(C + (size_t)(row0 + mi * 16 + row) * OUT_F + col0 + r * 4) = v;
      }
      asm volatile("" ::: "memory");          // gather(mi) before scatter(mi+1)
    }
  }
}

extern "C" void kernel_launch(void* const* d_in, const int* in_sizes, int n_in,
                              void* d_out, int out_size, void* d_ws, size_t ws_size,
                              hipStream_t stream) {
  const float* x    = (const float*)d_in[0];
  const int*   idx  = (const int*)d_in[1];
  const float* cb   = (const float*)d_in[2];
  const float* scl  = (const float*)d_in[3];
  const float* lA   = (const float*)d_in[4];
  const float* lB   = (const float*)d_in[5];
  const float* bias = (const float*)d_in[6];
  float* out = (float*)d_out;

  unsigned short* xb = (unsigned short*)d_ws;
  unsigned short* Wc = (unsigned short*)((char*)d_ws + (size_t)M_TOT * KDIM * 2);
  unsigned short* Lbuf = (unsigned short*)d_out;  // bf16 LoRA scratch; overwritten by k_gemm

  k_xcast<<<16384, 256, 0, stream>>>((const f32x4*)x, (u16x8*)xb);
  k_lora<<<dim3(16, 64), 256, 0, stream>>>(lA, lB, Lbuf);
  k_dequant<<<8192, 256, 0, stream>>>(idx, cb, scl, Lbuf, Wc);
  k_gemm<<<dim3(32, 16), 512, 0, stream>>>(xb, Wc, bias, out);
}